// Round 1
// baseline (105.604 us; speedup 1.0000x reference)
//
#include <hip/hip_runtime.h>

#define N_NODES 10000
#define IN_DIM  256
#define OUT_DIM 64
#define ALPHA   0.2f
#define CAP     256   // per-row LDS edge capacity (max degree ~66 expected; fallback path beyond)

// ---------------------------------------------------------------------------
// Kernel 1: Wh = X @ W  (N x 256 @ 256 x 64), fused with per-node scores
//           es[n] = Wh[n,:] . a[0:64],  ed[n] = Wh[n,:] . a[64:128]
// block = 256 threads (4 waves); block handles 32 rows; each wave 8 rows.
// lane = output column. W rows read coalesced (256B), X staged in LDS.
// ---------------------------------------------------------------------------
__global__ __launch_bounds__(256) void k_gemm(const float* __restrict__ X,
                                              const float* __restrict__ W,
                                              const float* __restrict__ a,
                                              float* __restrict__ Wh,
                                              float* __restrict__ es,
                                              float* __restrict__ ed) {
    __shared__ __align__(16) float xs[32][IN_DIM];   // 32 KB
    const int t = threadIdx.x;
    const int wave = t >> 6, lane = t & 63;
    const int base = blockIdx.x * 32;

    // stage 32 rows of X (32*64 float4 = 2048 float4, 8 per thread), coalesced
    for (int i = t; i < 32 * (IN_DIM / 4); i += 256) {
        int r  = i >> 6;         // local row
        int c4 = i & 63;         // float4 column
        int row = base + r;
        float4 v = (row < N_NODES) ? ((const float4*)X)[(size_t)row * (IN_DIM / 4) + c4]
                                   : make_float4(0.f, 0.f, 0.f, 0.f);
        ((float4*)&xs[r][0])[c4] = v;
    }
    __syncthreads();

    float acc[8];
#pragma unroll
    for (int i = 0; i < 8; ++i) acc[i] = 0.f;

    for (int kk = 0; kk < IN_DIM; kk += 4) {
        // one W column-slice per lane for 4 consecutive k (coalesced 256B loads)
        float w0 = W[(kk + 0) * OUT_DIM + lane];
        float w1 = W[(kk + 1) * OUT_DIM + lane];
        float w2 = W[(kk + 2) * OUT_DIM + lane];
        float w3 = W[(kk + 3) * OUT_DIM + lane];
#pragma unroll
        for (int r8 = 0; r8 < 8; ++r8) {
            float4 xv = *(const float4*)&xs[wave * 8 + r8][kk];  // broadcast b128
            acc[r8] = fmaf(xv.x, w0, acc[r8]);
            acc[r8] = fmaf(xv.y, w1, acc[r8]);
            acc[r8] = fmaf(xv.z, w2, acc[r8]);
            acc[r8] = fmaf(xv.w, w3, acc[r8]);
        }
    }

    const float asrc = a[lane];
    const float adst = a[OUT_DIM + lane];
#pragma unroll
    for (int r8 = 0; r8 < 8; ++r8) {
        int row = base + wave * 8 + r8;
        if (row < N_NODES) {
            float v = acc[r8];
            Wh[(size_t)row * OUT_DIM + lane] = v;
            float s1 = v * asrc;
            float s2 = v * adst;
#pragma unroll
            for (int o = 32; o > 0; o >>= 1) {
                s1 += __shfl_xor(s1, o, 64);
                s2 += __shfl_xor(s2, o, 64);
            }
            if (lane == 0) { es[row] = s1; ed[row] = s2; }
        }
    }
}

// ---------------------------------------------------------------------------
// CSR build: count -> exclusive scan -> fill
// ---------------------------------------------------------------------------
__global__ void k_count(const int* __restrict__ src, int E, int* __restrict__ cnt) {
    int i = blockIdx.x * 256 + threadIdx.x;
    if (i < E) atomicAdd(&cnt[src[i]], 1);
}

__global__ __launch_bounds__(1024) void k_scan(const int* __restrict__ cnt,
                                               int* __restrict__ off,
                                               int* __restrict__ cur,
                                               int n, int E) {
    __shared__ int part[1024];
    const int t = threadIdx.x;
    const int CH = (N_NODES + 1023) / 1024;  // 10
    int beg = t * CH, end = min(beg + CH, n);
    int s = 0;
    for (int i = beg; i < end; ++i) s += cnt[i];
    part[t] = s;
    __syncthreads();
    // Hillis-Steele inclusive scan over 1024 partials
    for (int d = 1; d < 1024; d <<= 1) {
        int v = (t >= d) ? part[t - d] : 0;
        __syncthreads();
        part[t] += v;
        __syncthreads();
    }
    int run = (t == 0) ? 0 : part[t - 1];
    for (int i = beg; i < end; ++i) {
        off[i] = run;
        cur[i] = run;
        run += cnt[i];
    }
    if (t == 0) off[n] = E;
}

__global__ void k_fill(const int* __restrict__ src, const int* __restrict__ dst, int E,
                       int* __restrict__ cur, int* __restrict__ csr) {
    int i = blockIdx.x * 256 + threadIdx.x;
    if (i < E) {
        int p = atomicAdd(&cur[src[i]], 1);
        csr[p] = dst[i];
    }
}

// ---------------------------------------------------------------------------
// Kernel 5: one wave per row. Dedupe duplicate (src,dst) pairs (softmax counts
// each unique pair ONCE; duplicate e-values are identical so which-wins is
// moot), softmax over the row's edges, accumulate h' = sum p_i/S * Wh[dst_i,:].
// lane = output dim -> Wh row loads are 256B coalesced, L2-resident.
// ---------------------------------------------------------------------------
__global__ __launch_bounds__(64) void k_attn(const int* __restrict__ off,
                                             const int* __restrict__ csr,
                                             const float* __restrict__ es,
                                             const float* __restrict__ ed,
                                             const float* __restrict__ Wh,
                                             float* __restrict__ out) {
    const int r = blockIdx.x;
    const int lane = threadIdx.x;
    const int beg = off[r];
    const int deg = off[r + 1] - beg;

    if (deg == 0) {
        // softmax of all-NEG_FILL row is uniform 1/N -> column mean of Wh
        float acc = 0.f;
        for (int j = 0; j < N_NODES; ++j) acc += Wh[(size_t)j * OUT_DIM + lane];
        out[(size_t)r * OUT_DIM + lane] = acc / (float)N_NODES;
        return;
    }

    const float er = es[r];
    __shared__ int   sdst[CAP];
    __shared__ float sp[CAP];

    if (deg <= CAP) {
        // pass A: load dst list
        for (int i = lane; i < deg; i += 64) sdst[i] = csr[beg + i];
        __syncthreads();
        // pass B: e + dedupe-mark + max
        float m = -INFINITY;
        for (int i = lane; i < deg; i += 64) {
            int d = sdst[i];
            bool first = true;
            for (int j = 0; j < i; ++j)
                if (sdst[j] == d) { first = false; break; }
            float e;
            if (first) {
                e = er + ed[d];
                e = e > 0.f ? e : ALPHA * e;
                m = fmaxf(m, e);
            } else {
                e = -INFINITY;   // excluded duplicates -> exp() == 0
            }
            sp[i] = e;
        }
#pragma unroll
        for (int o = 32; o > 0; o >>= 1) m = fmaxf(m, __shfl_xor(m, o, 64));
        __syncthreads();
        // pass C: exp + sum
        float ssum = 0.f;
        for (int i = lane; i < deg; i += 64) {
            float p = __expf(sp[i] - m);
            sp[i] = p;
            ssum += p;
        }
#pragma unroll
        for (int o = 32; o > 0; o >>= 1) ssum += __shfl_xor(ssum, o, 64);
        __syncthreads();
        // pass D: accumulate h'
        float acc = 0.f;
        for (int i = 0; i < deg; ++i) {
            float p = sp[i];           // LDS broadcast
            int   d = sdst[i];         // LDS broadcast
            acc = fmaf(p, Wh[(size_t)d * OUT_DIM + lane], acc);
        }
        out[(size_t)r * OUT_DIM + lane] = acc / ssum;
    } else {
        // generic fallback (deg > CAP): recompute from global, O(deg^2)
        float m = -INFINITY;
        for (int i = lane; i < deg; i += 64) {
            int d = csr[beg + i];
            bool first = true;
            for (int j = 0; j < i; ++j)
                if (csr[beg + j] == d) { first = false; break; }
            if (first) {
                float e = er + ed[d];
                e = e > 0.f ? e : ALPHA * e;
                m = fmaxf(m, e);
            }
        }
#pragma unroll
        for (int o = 32; o > 0; o >>= 1) m = fmaxf(m, __shfl_xor(m, o, 64));
        float ssum = 0.f;
        for (int i = lane; i < deg; i += 64) {
            int d = csr[beg + i];
            bool first = true;
            for (int j = 0; j < i; ++j)
                if (csr[beg + j] == d) { first = false; break; }
            if (first) {
                float e = er + ed[d];
                e = e > 0.f ? e : ALPHA * e;
                ssum += __expf(e - m);
            }
        }
#pragma unroll
        for (int o = 32; o > 0; o >>= 1) ssum += __shfl_xor(ssum, o, 64);
        float acc = 0.f;
        for (int i = 0; i < deg; ++i) {
            int d = csr[beg + i];
            bool first = true;
            for (int j = 0; j < i; ++j)
                if (csr[beg + j] == d) { first = false; break; }
            if (first) {
                float e = er + ed[d];
                e = e > 0.f ? e : ALPHA * e;
                acc = fmaf(__expf(e - m), Wh[(size_t)d * OUT_DIM + lane], acc);
            }
        }
        out[(size_t)r * OUT_DIM + lane] = acc / ssum;
    }
}

// ---------------------------------------------------------------------------
extern "C" void kernel_launch(void* const* d_in, const int* in_sizes, int n_in,
                              void* d_out, int out_size, void* d_ws, size_t ws_size,
                              hipStream_t stream) {
    const float* X     = (const float*)d_in[0];
    const int*   edges = (const int*)d_in[1];
    const float* W     = (const float*)d_in[2];
    const float* a     = (const float*)d_in[3];
    float* out = (float*)d_out;

    const int E = in_sizes[1] / 2;
    const int* src = edges;
    const int* dst = edges + E;

    // carve workspace (~4.3 MB total)
    char* ws = (char*)d_ws;
    size_t o = 0;
    auto carve = [&](size_t bytes) -> void* {
        o = (o + 255) & ~(size_t)255;
        void* p = ws + o;
        o += bytes;
        return p;
    };
    float* Wh  = (float*)carve((size_t)N_NODES * OUT_DIM * 4);
    float* es  = (float*)carve((size_t)N_NODES * 4);
    float* ed  = (float*)carve((size_t)N_NODES * 4);
    int*   cnt = (int*)carve((size_t)N_NODES * 4);
    int*   off = (int*)carve((size_t)(N_NODES + 1) * 4);
    int*   cur = (int*)carve((size_t)N_NODES * 4);
    int*   csr = (int*)carve((size_t)E * 4);

    hipMemsetAsync(cnt, 0, (size_t)N_NODES * 4, stream);
    k_gemm <<<(N_NODES + 31) / 32, 256, 0, stream>>>(X, W, a, Wh, es, ed);
    k_count<<<(E + 255) / 256, 256, 0, stream>>>(src, E, cnt);
    k_scan <<<1, 1024, 0, stream>>>(cnt, off, cur, N_NODES, E);
    k_fill <<<(E + 255) / 256, 256, 0, stream>>>(src, dst, E, cur, csr);
    k_attn <<<N_NODES, 64, 0, stream>>>(off, csr, es, ed, Wh, out);
}

// Round 2
// 69.062 us; speedup vs baseline: 1.5291x; 1.5291x over previous
//
#include <hip/hip_runtime.h>

#define N_NODES 10000
#define IN_DIM  256
#define OUT_DIM 64
#define ALPHA   0.2f
#define CAPS    128   // slot capacity per row (mean deg 32; P(deg>128) ~ 1e-40, clamped anyway)
#define CAP     256   // CSR-fallback LDS edge capacity

// ---------------------------------------------------------------------------
// Kernel 1: Wh = X @ W  (N x 256 @ 256 x 64), fused with per-node scores
//           es[n] = Wh[n,:] . a[0:64],  ed[n] = Wh[n,:] . a[64:128]
// Also zeroes the 10000-int counter array (zero10k) for the next kernel --
// saves a separate fill dispatch (tiny fills cost ~40us as standalone
// dispatches in this latency-bound regime).
// ---------------------------------------------------------------------------
__global__ __launch_bounds__(256) void k_gemm(const float* __restrict__ X,
                                              const float* __restrict__ W,
                                              const float* __restrict__ a,
                                              float* __restrict__ Wh,
                                              float* __restrict__ es,
                                              float* __restrict__ ed,
                                              int* __restrict__ zero10k) {
    const int t = threadIdx.x;
    const int gid = blockIdx.x * 256 + t;
    if (gid < N_NODES) zero10k[gid] = 0;

    __shared__ __align__(16) float xs[32][IN_DIM];   // 32 KB
    const int wave = t >> 6, lane = t & 63;
    const int base = blockIdx.x * 32;

    // stage 32 rows of X (2048 float4, 8 per thread), coalesced
    for (int i = t; i < 32 * (IN_DIM / 4); i += 256) {
        int r  = i >> 6;
        int c4 = i & 63;
        int row = base + r;
        float4 v = (row < N_NODES) ? ((const float4*)X)[(size_t)row * (IN_DIM / 4) + c4]
                                   : make_float4(0.f, 0.f, 0.f, 0.f);
        ((float4*)&xs[r][0])[c4] = v;
    }
    __syncthreads();

    float acc[8];
#pragma unroll
    for (int i = 0; i < 8; ++i) acc[i] = 0.f;

    for (int kk = 0; kk < IN_DIM; kk += 4) {
        float w0 = W[(kk + 0) * OUT_DIM + lane];
        float w1 = W[(kk + 1) * OUT_DIM + lane];
        float w2 = W[(kk + 2) * OUT_DIM + lane];
        float w3 = W[(kk + 3) * OUT_DIM + lane];
#pragma unroll
        for (int r8 = 0; r8 < 8; ++r8) {
            float4 xv = *(const float4*)&xs[wave * 8 + r8][kk];  // LDS broadcast b128
            acc[r8] = fmaf(xv.x, w0, acc[r8]);
            acc[r8] = fmaf(xv.y, w1, acc[r8]);
            acc[r8] = fmaf(xv.z, w2, acc[r8]);
            acc[r8] = fmaf(xv.w, w3, acc[r8]);
        }
    }

    const float asrc = a[lane];
    const float adst = a[OUT_DIM + lane];
#pragma unroll
    for (int r8 = 0; r8 < 8; ++r8) {
        int row = base + wave * 8 + r8;
        if (row < N_NODES) {
            float v = acc[r8];
            Wh[(size_t)row * OUT_DIM + lane] = v;
            float s1 = v * asrc;
            float s2 = v * adst;
#pragma unroll
            for (int o = 32; o > 0; o >>= 1) {
                s1 += __shfl_xor(s1, o, 64);
                s2 += __shfl_xor(s2, o, 64);
            }
            if (lane == 0) { es[row] = s1; ed[row] = s2; }
        }
    }
}

// ---------------------------------------------------------------------------
// FAST PATH kernel 2: scatter edges into fixed-stride per-row buckets.
// Stores {dst, ed[dst]} so the attention kernel never does scattered gathers.
// ---------------------------------------------------------------------------
__global__ void k_fill_slots(const int* __restrict__ src, const int* __restrict__ dst,
                             int E, const float* __restrict__ ed,
                             int* __restrict__ cur, int2* __restrict__ slots) {
    int i = blockIdx.x * 256 + threadIdx.x;
    if (i < E) {
        int s = src[i], d = dst[i];
        float ev = ed[d];                 // scattered 4B load; 40KB table, L1/L2-resident
        int p = atomicAdd(&cur[s], 1);
        if (p < CAPS) slots[(size_t)s * CAPS + p] = make_int2(d, __float_as_int(ev));
    }
}

// ---------------------------------------------------------------------------
// FAST PATH kernel 3: one wave per row. Dedupe duplicate (src,dst) pairs
// (reference .at[].set counts each pair once; duplicate e identical), softmax,
// h' = sum p_i/S * Wh[dst_i,:]. lane = output dim -> 256B coalesced Wh rows.
// ---------------------------------------------------------------------------
__global__ __launch_bounds__(64) void k_attn_slots(const int* __restrict__ cur,
                                                   const int2* __restrict__ slots,
                                                   const float* __restrict__ es,
                                                   const float* __restrict__ Wh,
                                                   float* __restrict__ out) {
    const int r = blockIdx.x;
    const int lane = threadIdx.x;
    int deg = cur[r];
    if (deg > CAPS) deg = CAPS;

    if (deg == 0) {
        // softmax of all-NEG_FILL row is uniform -> column mean of Wh
        float acc = 0.f;
        for (int j = 0; j < N_NODES; ++j) acc += Wh[(size_t)j * OUT_DIM + lane];
        out[(size_t)r * OUT_DIM + lane] = acc / (float)N_NODES;
        return;
    }

    const float er = es[r];
    __shared__ int   sdst[CAPS];
    __shared__ float sp[CAPS];

    // pass A: load slot pairs, compute leaky-relu e
    for (int i = lane; i < deg; i += 64) {
        int2 v = slots[(size_t)r * CAPS + i];
        sdst[i] = v.x;
        float e = er + __int_as_float(v.y);
        sp[i] = e > 0.f ? e : ALPHA * e;
    }
    __syncthreads();

    // pass B: dedupe-mark + row max
    float m = -INFINITY;
    for (int i = lane; i < deg; i += 64) {
        int d = sdst[i];
        bool first = true;
        for (int j = 0; j < i; ++j)
            if (sdst[j] == d) { first = false; break; }
        if (first) m = fmaxf(m, sp[i]);
        else       sp[i] = -INFINITY;     // exp() -> 0
    }
#pragma unroll
    for (int o = 32; o > 0; o >>= 1) m = fmaxf(m, __shfl_xor(m, o, 64));
    __syncthreads();

    // pass C: exp + sum
    float ssum = 0.f;
    for (int i = lane; i < deg; i += 64) {
        float p = __expf(sp[i] - m);
        sp[i] = p;
        ssum += p;
    }
#pragma unroll
    for (int o = 32; o > 0; o >>= 1) ssum += __shfl_xor(ssum, o, 64);
    __syncthreads();

    // pass D: accumulate h'
    float acc = 0.f;
    for (int i = 0; i < deg; ++i) {
        float p = sp[i];                  // LDS broadcast
        int   d = sdst[i];                // LDS broadcast
        acc = fmaf(p, Wh[(size_t)d * OUT_DIM + lane], acc);
    }
    out[(size_t)r * OUT_DIM + lane] = acc / ssum;
}

// ---------------------------------------------------------------------------
// CSR FALLBACK (used only if ws_size can't hold the slot buckets) — proven
// round-1 path minus the memset dispatch.
// ---------------------------------------------------------------------------
__global__ void k_count(const int* __restrict__ src, int E, int* __restrict__ cnt) {
    int i = blockIdx.x * 256 + threadIdx.x;
    if (i < E) atomicAdd(&cnt[src[i]], 1);
}

__global__ __launch_bounds__(1024) void k_scan(const int* __restrict__ cnt,
                                               int* __restrict__ off,
                                               int* __restrict__ cur,
                                               int n, int E) {
    __shared__ int part[1024];
    const int t = threadIdx.x;
    const int CH = (N_NODES + 1023) / 1024;
    int beg = t * CH, end = min(beg + CH, n);
    int s = 0;
    for (int i = beg; i < end; ++i) s += cnt[i];
    part[t] = s;
    __syncthreads();
    for (int d = 1; d < 1024; d <<= 1) {
        int v = (t >= d) ? part[t - d] : 0;
        __syncthreads();
        part[t] += v;
        __syncthreads();
    }
    int run = (t == 0) ? 0 : part[t - 1];
    for (int i = beg; i < end; ++i) {
        off[i] = run;
        cur[i] = run;
        run += cnt[i];
    }
    if (t == 0) off[n] = E;
}

__global__ void k_fill(const int* __restrict__ src, const int* __restrict__ dst, int E,
                       int* __restrict__ cur, int* __restrict__ csr) {
    int i = blockIdx.x * 256 + threadIdx.x;
    if (i < E) {
        int p = atomicAdd(&cur[src[i]], 1);
        csr[p] = dst[i];
    }
}

__global__ __launch_bounds__(64) void k_attn(const int* __restrict__ off,
                                             const int* __restrict__ csr,
                                             const float* __restrict__ es,
                                             const float* __restrict__ ed,
                                             const float* __restrict__ Wh,
                                             float* __restrict__ out) {
    const int r = blockIdx.x;
    const int lane = threadIdx.x;
    const int beg = off[r];
    const int deg = off[r + 1] - beg;

    if (deg == 0) {
        float acc = 0.f;
        for (int j = 0; j < N_NODES; ++j) acc += Wh[(size_t)j * OUT_DIM + lane];
        out[(size_t)r * OUT_DIM + lane] = acc / (float)N_NODES;
        return;
    }

    const float er = es[r];
    __shared__ int   sdst[CAP];
    __shared__ float sp[CAP];

    if (deg <= CAP) {
        for (int i = lane; i < deg; i += 64) sdst[i] = csr[beg + i];
        __syncthreads();
        float m = -INFINITY;
        for (int i = lane; i < deg; i += 64) {
            int d = sdst[i];
            bool first = true;
            for (int j = 0; j < i; ++j)
                if (sdst[j] == d) { first = false; break; }
            float e;
            if (first) {
                e = er + ed[d];
                e = e > 0.f ? e : ALPHA * e;
                m = fmaxf(m, e);
            } else e = -INFINITY;
            sp[i] = e;
        }
#pragma unroll
        for (int o = 32; o > 0; o >>= 1) m = fmaxf(m, __shfl_xor(m, o, 64));
        __syncthreads();
        float ssum = 0.f;
        for (int i = lane; i < deg; i += 64) {
            float p = __expf(sp[i] - m);
            sp[i] = p;
            ssum += p;
        }
#pragma unroll
        for (int o = 32; o > 0; o >>= 1) ssum += __shfl_xor(ssum, o, 64);
        __syncthreads();
        float acc = 0.f;
        for (int i = 0; i < deg; ++i)
            acc = fmaf(sp[i], Wh[(size_t)sdst[i] * OUT_DIM + lane], acc);
        out[(size_t)r * OUT_DIM + lane] = acc / ssum;
    } else {
        float m = -INFINITY;
        for (int i = lane; i < deg; i += 64) {
            int d = csr[beg + i];
            bool first = true;
            for (int j = 0; j < i; ++j)
                if (csr[beg + j] == d) { first = false; break; }
            if (first) {
                float e = er + ed[d];
                e = e > 0.f ? e : ALPHA * e;
                m = fmaxf(m, e);
            }
        }
#pragma unroll
        for (int o = 32; o > 0; o >>= 1) m = fmaxf(m, __shfl_xor(m, o, 64));
        float ssum = 0.f;
        for (int i = lane; i < deg; i += 64) {
            int d = csr[beg + i];
            bool first = true;
            for (int j = 0; j < i; ++j)
                if (csr[beg + j] == d) { first = false; break; }
            if (first) {
                float e = er + ed[d];
                e = e > 0.f ? e : ALPHA * e;
                ssum += __expf(e - m);
            }
        }
#pragma unroll
        for (int o = 32; o > 0; o >>= 1) ssum += __shfl_xor(ssum, o, 64);
        float acc = 0.f;
        for (int i = 0; i < deg; ++i) {
            int d = csr[beg + i];
            bool first = true;
            for (int j = 0; j < i; ++j)
                if (csr[beg + j] == d) { first = false; break; }
            if (first) {
                float e = er + ed[d];
                e = e > 0.f ? e : ALPHA * e;
                acc = fmaf(__expf(e - m), Wh[(size_t)d * OUT_DIM + lane], acc);
            }
        }
        out[(size_t)r * OUT_DIM + lane] = acc / ssum;
    }
}

// ---------------------------------------------------------------------------
extern "C" void kernel_launch(void* const* d_in, const int* in_sizes, int n_in,
                              void* d_out, int out_size, void* d_ws, size_t ws_size,
                              hipStream_t stream) {
    const float* X     = (const float*)d_in[0];
    const int*   edges = (const int*)d_in[1];
    const float* W     = (const float*)d_in[2];
    const float* a     = (const float*)d_in[3];
    float* out = (float*)d_out;

    const int E = in_sizes[1] / 2;
    const int* src = edges;
    const int* dst = edges + E;

    char* ws = (char*)d_ws;
    size_t o = 0;
    auto carve = [&](size_t bytes) -> void* {
        o = (o + 255) & ~(size_t)255;
        void* p = ws + o;
        o += bytes;
        return p;
    };
    float* Wh  = (float*)carve((size_t)N_NODES * OUT_DIM * 4);
    float* es  = (float*)carve((size_t)N_NODES * 4);
    float* ed  = (float*)carve((size_t)N_NODES * 4);
    int*   cur = (int*)carve((size_t)N_NODES * 4);

    // fast path needs the slot buckets on top of the above
    size_t slots_off = (o + 255) & ~(size_t)255;
    size_t need_fast = slots_off + (size_t)N_NODES * CAPS * 8;

    if (ws_size >= need_fast) {
        int2* slots = (int2*)(ws + slots_off);
        k_gemm      <<<(N_NODES + 31) / 32, 256, 0, stream>>>(X, W, a, Wh, es, ed, cur);
        k_fill_slots<<<(E + 255) / 256, 256, 0, stream>>>(src, dst, E, ed, cur, slots);
        k_attn_slots<<<N_NODES, 64, 0, stream>>>(cur, slots, es, Wh, out);
    } else {
        int* cnt = (int*)carve((size_t)N_NODES * 4);
        int* off = (int*)carve((size_t)(N_NODES + 1) * 4);
        int* csr = (int*)carve((size_t)E * 4);
        k_gemm <<<(N_NODES + 31) / 32, 256, 0, stream>>>(X, W, a, Wh, es, ed, cnt);
        k_count<<<(E + 255) / 256, 256, 0, stream>>>(src, E, cnt);
        k_scan <<<1, 1024, 0, stream>>>(cnt, off, cur, N_NODES, E);
        k_fill <<<(E + 255) / 256, 256, 0, stream>>>(src, dst, E, cur, csr);
        k_attn <<<N_NODES, 64, 0, stream>>>(off, csr, es, ed, Wh, out);
    }
}